// Round 4
// baseline (313.774 us; speedup 1.0000x reference)
//
#include <hip/hip_runtime.h>
#include <stdint.h>

#define NN 16384
#define UU 128
#define CAP 128

typedef unsigned short u16;
typedef unsigned int uv4 __attribute__((ext_vector_type(4)));  // nt-load-able

// Gather-sum of x-rows listed in sIdx[0..c): 2-way k-parallel (wave halves),
// float4 per lane (32 lanes * 16B = one 512B row per k-slot). After the
// shfl_xor(32) reduce both halves hold the full row-sum.
__device__ __forceinline__ float4 gather_row_sum(const float* __restrict__ src,
                                                 const u16* sIdx, int c,
                                                 int half, int sl) {
    float4 acc = {0.f, 0.f, 0.f, 0.f};
#pragma unroll 8
    for (int k = half; k < c; k += 2) {
        const int j = sIdx[k];                                  // LDS broadcast
        const float4 v = *reinterpret_cast<const float4*>(src + (size_t)j * UU + sl * 4);
        acc.x += v.x; acc.y += v.y; acc.z += v.z; acc.w += v.w;
    }
    acc.x += __shfl_xor(acc.x, 32);
    acc.y += __shfl_xor(acc.y, 32);
    acc.z += __shfl_xor(acc.z, 32);
    acc.w += __shfl_xor(acc.w, 32);
    return acc;
}

// Per-row dense linear + swish: each lane produces 2 features from sNeigh row.
__device__ __forceinline__ void row_linear_swish(const float* sNeighRow,
                                                 const float* __restrict__ W,
                                                 const float* __restrict__ bias,
                                                 float* __restrict__ dst,
                                                 int row, int lane) {
    const float2* W2 = reinterpret_cast<const float2*>(W);
    const float2 b2 = reinterpret_cast<const float2*>(bias)[lane];
    float f0 = b2.x, f1 = b2.y;
    for (int v = 0; v < UU; ++v) {
        const float nv = sNeighRow[v];             // LDS broadcast
        const float2 w = W2[v * 64 + lane];        // coalesced, cache-resident
        f0 += nv * w.x;
        f1 += nv * w.y;
    }
    float2 o;
    o.x = f0 / (1.0f + __expf(-f0));
    o.y = f1 / (1.0f + __expf(-f1));
    *reinterpret_cast<float2*>(dst + (size_t)row * UU + lane * 2) = o;
}

// ---------------------------------------------------------------------------
// Kernel A: fused sparsify + hop1. One wave per row.
//  phase 1: ballot-scan adj row -> neighbor indices in LDS (+ mirror to ELL)
//           with wave-uniform early-outs (most 256-elem groups are all-zero)
//  phase 2: gather-sum x rows (hidden under other waves' adj streaming)
//  phase 3: per-row 128x128 GEMM + bias + swish -> x1
// ---------------------------------------------------------------------------
__global__ __launch_bounds__(256) void fused_sparsify_hop1(
    const float* __restrict__ adj, const float* __restrict__ x,
    const float* __restrict__ W, const float* __restrict__ bias,
    float* __restrict__ x1, u16* __restrict__ ell, unsigned* __restrict__ cnt) {
    __shared__ u16   sIdx[4][CAP];
    __shared__ float sNeigh[4][UU];

    const int wave = threadIdx.x >> 6;
    const int lane = threadIdx.x & 63;
    const int row  = blockIdx.x * 4 + wave;

    // ---- phase 1: scan (reads adj exactly once, coalesced nt 16B loads)
    const uv4* rowp = reinterpret_cast<const uv4*>(adj + (size_t)row * NN);
    unsigned count = 0;
    const unsigned long long below = (lane == 63) ? 0x7fffffffffffffffull
                                                  : ((1ull << lane) - 1ull);
    for (int it = 0; it < NN / 256; ++it) {
        const uv4 v = __builtin_nontemporal_load(&rowp[it * 64 + lane]);
        const unsigned any4 = v.x | v.y | v.z | v.w;   // 0.0f==0 bits, 1.0f!=0
        if (__any(any4 != 0u)) {
            unsigned col0 = (unsigned)((it * 64 + lane) * 4);
            unsigned vals[4] = {v.x, v.y, v.z, v.w};
#pragma unroll
            for (int e = 0; e < 4; ++e) {
                bool nz = (vals[e] != 0u);
                unsigned long long m = __ballot(nz);
                if (m != 0ull) {                       // wave-uniform branch
                    if (nz) {
                        unsigned pos = count + (unsigned)__popcll(m & below);
                        if (pos < CAP) sIdx[wave][pos] = (u16)(col0 + e);
                    }
                    count += (unsigned)__popcll(m);
                }
            }
        }
    }
    const int c = (count < CAP) ? (int)count : CAP;
    if (lane == 0) cnt[row] = (unsigned)c;
    __syncthreads();

    // mirror ELL to global for hop2
    for (int p = lane; p < c; p += 64) ell[(size_t)row * CAP + p] = sIdx[wave][p];

    // ---- phase 2: gather
    const int half = lane >> 5;
    const int sl   = lane & 31;
    float4 acc = gather_row_sum(x, sIdx[wave], c, half, sl);
    if (half == 0) *reinterpret_cast<float4*>(&sNeigh[wave][sl * 4]) = acc;
    __syncthreads();

    // ---- phase 3: per-row GEMM + swish
    row_linear_swish(sNeigh[wave], W, bias, x1, row, lane);
}

// ---------------------------------------------------------------------------
// Kernel B: fused hop2 = gather + GEMM + swish -> out. One wave per row;
// indices pre-staged in LDS for full memory-level parallelism.
// ---------------------------------------------------------------------------
__global__ __launch_bounds__(256) void fused_hop2(
    const float* __restrict__ x1, const u16* __restrict__ ell,
    const unsigned* __restrict__ cnt, const float* __restrict__ W,
    const float* __restrict__ bias, float* __restrict__ out) {
    __shared__ u16   sIdx[4][CAP];
    __shared__ float sNeigh[4][UU];

    const int wave = threadIdx.x >> 6;
    const int lane = threadIdx.x & 63;
    const int row  = blockIdx.x * 4 + wave;

    const int c = (int)cnt[row];
    sIdx[wave][lane]      = ell[(size_t)row * CAP + lane];
    sIdx[wave][lane + 64] = ell[(size_t)row * CAP + 64 + lane];
    __syncthreads();

    const int half = lane >> 5;
    const int sl   = lane & 31;
    float4 acc = gather_row_sum(x1, sIdx[wave], c, half, sl);
    if (half == 0) *reinterpret_cast<float4*>(&sNeigh[wave][sl * 4]) = acc;
    __syncthreads();

    row_linear_swish(sNeigh[wave], W, bias, out, row, lane);
}

// ---------------------------------------------------------------------------
extern "C" void kernel_launch(void* const* d_in, const int* in_sizes, int n_in,
                              void* d_out, int out_size, void* d_ws, size_t ws_size,
                              hipStream_t stream) {
    const float* x   = (const float*)d_in[0];   // [N, U]
    const float* adj = (const float*)d_in[1];   // [N, N]
    const float* W   = (const float*)d_in[2];   // [U, U]
    const float* b   = (const float*)d_in[3];   // [U]
    float* out = (float*)d_out;                 // [N, U] fp32

    char* ws = (char*)d_ws;
    float*    x1  = (float*)(ws);                                  // 8 MB
    u16*      ell = (u16*)  (ws + (size_t)8 * 1024 * 1024);        // 4 MB
    unsigned* cnt = (unsigned*)(ws + (size_t)12 * 1024 * 1024);    // 64 KB

    fused_sparsify_hop1<<<NN / 4, 256, 0, stream>>>(adj, x, W, b, x1, ell, cnt);
    fused_hop2<<<NN / 4, 256, 0, stream>>>(x1, ell, cnt, W, b, out);
}

// Round 5
// 264.439 us; speedup vs baseline: 1.1866x; 1.1866x over previous
//
#include <hip/hip_runtime.h>
#include <stdint.h>

#define NN 16384
#define UU 128
#define CAP 128

typedef unsigned short u16;

// Gather-sum of x-rows listed in sIdx[0..c): 2-way k-parallel (wave halves),
// float4 per lane (32 lanes * 16B = one 512B row per k-slot). After the
// shfl_xor(32) reduce both halves hold the full row-sum.
__device__ __forceinline__ float4 gather_row_sum(const float* __restrict__ src,
                                                 const u16* sIdx, int c,
                                                 int half, int sl) {
    float4 acc = {0.f, 0.f, 0.f, 0.f};
#pragma unroll 8
    for (int k = half; k < c; k += 2) {
        const int j = sIdx[k];                                  // LDS broadcast
        const float4 v = *reinterpret_cast<const float4*>(src + (size_t)j * UU + sl * 4);
        acc.x += v.x; acc.y += v.y; acc.z += v.z; acc.w += v.w;
    }
    acc.x += __shfl_xor(acc.x, 32);
    acc.y += __shfl_xor(acc.y, 32);
    acc.z += __shfl_xor(acc.z, 32);
    acc.w += __shfl_xor(acc.w, 32);
    return acc;
}

// Block-cooperative GEMM + swish over the 4 rows staged in sNeigh.
// 256 threads = 128 features x 2 row-groups; each W element feeds 2 FMAs,
// and both half-groups read the same W line (L1 broadcast) -> 4x less W
// traffic than per-wave GEMM.
__device__ __forceinline__ void block_linear_swish(const float (*sNeigh)[UU],
                                                   const float* __restrict__ W,
                                                   const float* __restrict__ bias,
                                                   float* __restrict__ dst,
                                                   int rowBase, int tid) {
    const int u = tid & 127;
    const int g = tid >> 7;            // rows 2g, 2g+1
    const float bu = bias[u];
    float f0 = bu, f1 = bu;
    for (int v = 0; v < UU; ++v) {
        const float w = W[v * UU + u];              // coalesced, cache-resident
        f0 += sNeigh[2 * g + 0][v] * w;             // LDS broadcast (uniform v)
        f1 += sNeigh[2 * g + 1][v] * w;
    }
    const float s0 = f0 / (1.0f + __expf(-f0));
    const float s1 = f1 / (1.0f + __expf(-f1));
    dst[(size_t)(rowBase + 2 * g + 0) * UU + u] = s0;
    dst[(size_t)(rowBase + 2 * g + 1) * UU + u] = s1;
}

// ---------------------------------------------------------------------------
// Kernel A: fused sparsify + hop1. One wave per row, 4 rows per block.
//  phase 1: branch-free ballot-scan of adj row -> indices in LDS (+ ELL mirror)
//  phase 2: gather-sum x rows (hidden under other waves' adj streaming)
//  phase 3: block-cooperative 4-row GEMM + bias + swish -> x1
// ---------------------------------------------------------------------------
__global__ __launch_bounds__(256) void fused_sparsify_hop1(
    const float* __restrict__ adj, const float* __restrict__ x,
    const float* __restrict__ W, const float* __restrict__ bias,
    float* __restrict__ x1, u16* __restrict__ ell, unsigned* __restrict__ cnt) {
    __shared__ u16   sIdx[4][CAP];
    __shared__ float sNeigh[4][UU];

    const int tid  = threadIdx.x;
    const int wave = tid >> 6;
    const int lane = tid & 63;
    const int rowBase = blockIdx.x * 4;
    const int row  = rowBase + wave;

    // ---- phase 1: scan (reads adj exactly once, coalesced uint4, branch-free)
    const uint4* rowp = reinterpret_cast<const uint4*>(adj + (size_t)row * NN);
    unsigned count = 0;
    const unsigned long long below = (lane == 63) ? 0x7fffffffffffffffull
                                                  : ((1ull << lane) - 1ull);
    for (int it = 0; it < NN / 256; ++it) {
        uint4 v = rowp[it * 64 + lane];
        unsigned col0 = (unsigned)((it * 64 + lane) * 4);
        unsigned vals[4] = {v.x, v.y, v.z, v.w};
#pragma unroll
        for (int e = 0; e < 4; ++e) {
            bool nz = (vals[e] != 0u);            // exact 0.0f vs 1.0f bits
            unsigned long long m = __ballot(nz);
            if (nz) {
                unsigned pos = count + (unsigned)__popcll(m & below);
                if (pos < CAP) sIdx[wave][pos] = (u16)(col0 + e);
            }
            count += (unsigned)__popcll(m);
        }
    }
    const int c = (count < CAP) ? (int)count : CAP;
    if (lane == 0) cnt[row] = (unsigned)c;

    // mirror ELL to global for hop2 (per-wave, no barrier needed)
    for (int p = lane; p < c; p += 64) ell[(size_t)row * CAP + p] = sIdx[wave][p];

    // ---- phase 2: gather (same wave that built sIdx -> no barrier needed)
    const int half = lane >> 5;
    const int sl   = lane & 31;
    float4 acc = gather_row_sum(x, sIdx[wave], c, half, sl);
    if (half == 0) *reinterpret_cast<float4*>(&sNeigh[wave][sl * 4]) = acc;
    __syncthreads();

    // ---- phase 3: block-cooperative GEMM + swish
    block_linear_swish(sNeigh, W, bias, x1, rowBase, tid);
}

// ---------------------------------------------------------------------------
// Kernel B: fused hop2 = gather + block GEMM + swish -> out. One wave per row;
// indices pre-staged in LDS for full memory-level parallelism.
// ---------------------------------------------------------------------------
__global__ __launch_bounds__(256) void fused_hop2(
    const float* __restrict__ x1, const u16* __restrict__ ell,
    const unsigned* __restrict__ cnt, const float* __restrict__ W,
    const float* __restrict__ bias, float* __restrict__ out) {
    __shared__ u16   sIdx[4][CAP];
    __shared__ float sNeigh[4][UU];

    const int tid  = threadIdx.x;
    const int wave = tid >> 6;
    const int lane = tid & 63;
    const int rowBase = blockIdx.x * 4;
    const int row  = rowBase + wave;

    const int c = (int)cnt[row];
    // stage the wave's index list: 64 lanes x ushort2 = 128 u16, coalesced
    const ushort2* ellRow = reinterpret_cast<const ushort2*>(ell + (size_t)row * CAP);
    reinterpret_cast<ushort2*>(sIdx[wave])[lane] = ellRow[lane];

    const int half = lane >> 5;
    const int sl   = lane & 31;
    float4 acc = gather_row_sum(x1, sIdx[wave], c, half, sl);
    if (half == 0) *reinterpret_cast<float4*>(&sNeigh[wave][sl * 4]) = acc;
    __syncthreads();

    block_linear_swish(sNeigh, W, bias, out, rowBase, tid);
}

// ---------------------------------------------------------------------------
extern "C" void kernel_launch(void* const* d_in, const int* in_sizes, int n_in,
                              void* d_out, int out_size, void* d_ws, size_t ws_size,
                              hipStream_t stream) {
    const float* x   = (const float*)d_in[0];   // [N, U]
    const float* adj = (const float*)d_in[1];   // [N, N]
    const float* W   = (const float*)d_in[2];   // [U, U]
    const float* b   = (const float*)d_in[3];   // [U]
    float* out = (float*)d_out;                 // [N, U] fp32

    char* ws = (char*)d_ws;
    float*    x1  = (float*)(ws);                                  // 8 MB
    u16*      ell = (u16*)  (ws + (size_t)8 * 1024 * 1024);        // 4 MB
    unsigned* cnt = (unsigned*)(ws + (size_t)12 * 1024 * 1024);    // 64 KB

    fused_sparsify_hop1<<<NN / 4, 256, 0, stream>>>(adj, x, W, b, x1, ell, cnt);
    fused_hop2<<<NN / 4, 256, 0, stream>>>(x1, ell, cnt, W, b, out);
}